// Round 11
// baseline (716.283 us; speedup 1.0000x reference)
//
#include <hip/hip_runtime.h>
#include <math.h>

#define NN 50000
#define EE 1600000
#define IN_DIM 256
#define H_DIM 64
#define C_DIM 16
#define NT 5000
#define NBUK 391  // ceil(NN/128)
#define CHUNK 4096
#define NCHUNK 391  // ceil(EE/CHUNK)
#define PAD 6144   // per-bucket temp capacity
#define CAP 6144
#define RSTRIDE 128  // 16 groups x 8 slots, group-major; neighbor idx i -> (i&15)*8 + (i>>4)

typedef short bf16x8 __attribute__((ext_vector_type(8)));
typedef float f32x4 __attribute__((ext_vector_type(4)));
typedef unsigned short us8 __attribute__((ext_vector_type(8)));

__device__ __forceinline__ unsigned short f2bf(float f) {
    unsigned int u = __float_as_uint(f);
    u = (u + 0x7FFFu + ((u >> 16) & 1u)) >> 16;  // RNE
    return (unsigned short)u;
}
// bf16x2 dword accumulate via v_dot2_f32_bf16 (bit-identical to extract+add).
__device__ __forceinline__ void acc_dw(float2& a, unsigned u) {
    asm("v_dot2_f32_bf16 %0, %1, %2, %0" : "+v"(a.x) : "v"(u), "v"(0x00003F80u));
    asm("v_dot2_f32_bf16 %0, %1, %2, %0" : "+v"(a.y) : "v"(u), "v"(0x3F800000u));
}
__device__ __forceinline__ void acc_u4(float2* acc, uint4 v) {
    acc_dw(acc[0], v.x); acc_dw(acc[1], v.y); acc_dw(acc[2], v.z); acc_dw(acc[3], v.w);
}

// ---------------- init ----------------
__global__ __launch_bounds__(256) void init_kernel(const float* __restrict__ W1, const float* __restrict__ W2,
                                                   unsigned short* __restrict__ WT1, unsigned short* __restrict__ WT2,
                                                   int* __restrict__ cursor, float* __restrict__ loss_ws,
                                                   int* __restrict__ done_ct, int* __restrict__ train_cnt) {
    int i = blockIdx.x * 256 + threadIdx.x;
    if (i < NBUK) cursor[i] = i * PAD;
    if (i < NN) train_cnt[i] = 0;
    if (i == 0) { loss_ws[0] = 0.f; done_ct[0] = 0; }
    if (i < 64 * 256) {
        int n = i >> 8, k = i & 255;
        WT1[i] = f2bf(W1[k * 64 + n]);
    }
    int j = i - 64 * 256;
    if (j >= 0 && j < 2 * 64 * 64) {
        int l = j >> 12, r = j & 4095;
        int n = r >> 6, k = r & 63;
        WT2[j] = f2bf(W2[l * 4096 + k * 64 + n]);
    }
}

// ---------------- multisplit (verified) ----------------
__global__ __launch_bounds__(512) void multisplit_kernel(const int* __restrict__ src, const int* __restrict__ dst,
                                                         int* __restrict__ cursor, unsigned int* __restrict__ temp) {
    __shared__ int hist[NBUK];
    __shared__ int excl[NBUK + 1];
    __shared__ int offs[NBUK];
    __shared__ int delta[NBUK];
    __shared__ unsigned int stag[CHUNK];
    __shared__ unsigned short sdl[CHUNK];

    const int tid = threadIdx.x;
    const int base_e = blockIdx.x * CHUNK;

    for (int i = tid; i < NBUK; i += 512) hist[i] = 0;
    __syncthreads();

    for (int i = tid; i < CHUNK; i += 512) {
        int e = base_e + i;
        if (e < EE) {
            int d = dst[e];
            atomicAdd(&hist[d >> 7], 1);
            sdl[i] = (unsigned short)d;
        }
    }
    __syncthreads();

    if (tid < 64) {
        int lane = tid;
        int lc[7];
        int s = 0;
#pragma unroll
        for (int k = 0; k < 7; ++k) {
            int idx = lane * 7 + k;
            int c = (idx < NBUK) ? hist[idx] : 0;
            lc[k] = c;
            s += c;
        }
        int v = s;
#pragma unroll
        for (int off = 1; off < 64; off <<= 1) {
            int u = __shfl_up(v, off);
            if (lane >= off) v += u;
        }
        int ex = v - s;
#pragma unroll
        for (int k = 0; k < 7; ++k) {
            int idx = lane * 7 + k;
            if (idx < NBUK) excl[idx] = ex;
            ex += lc[k];
        }
        if (lane == 63) excl[NBUK] = v;
    }
    __syncthreads();

    for (int b = tid; b < NBUK; b += 512) {
        int count = excl[b + 1] - excl[b];
        int gbase = atomicAdd(&cursor[b], count);
        delta[b] = gbase - excl[b];
        offs[b] = excl[b];
    }
    __syncthreads();

    for (int i = tid; i < CHUNK; i += 512) {
        int e = base_e + i;
        if (e < EE) {
            unsigned int dv = sdl[i];
            int b = (int)(dv >> 7);
            int rank = atomicAdd(&offs[b], 1);
            stag[rank] = ((unsigned)b << 23) | ((dv & 127u) << 16) | (unsigned)src[e];
        }
    }
    __syncthreads();

    int nval = excl[NBUK];
    for (int i = tid; i < nval; i += 512) {
        unsigned int v = stag[i];
        temp[delta[v >> 23] + i] = v & 0x7FFFFFu;
    }
}

// ---------------- per-bucket finalize: 16x8 group-major rows + train histogram ----------------
__global__ __launch_bounds__(512) void bucket_finalize_kernel(const unsigned int* __restrict__ temp,
                                                              const int* __restrict__ cursor,
                                                              float* __restrict__ dinv,
                                                              unsigned short* __restrict__ col16,
                                                              const int* __restrict__ train_idx,
                                                              int* __restrict__ train_cnt) {
    __shared__ int cnt2[128];
    __shared__ unsigned short stag2[128 * RSTRIDE];  // 32 KB
    const int b = blockIdx.x;
    const int tid = threadIdx.x;
    // train histogram (train_cnt zeroed in init, kernel-ordered before us)
    if (b < 10) {
        int i = b * 512 + tid;
        if (i < NT) atomicAdd(&train_cnt[train_idx[i]], 1);
    }
    const int d0 = b << 7;
    const int nd = (d0 + 128 < NN) ? 128 : (NN - d0);
    const int base = b * PAD;
    int M = cursor[b] - base;
    if (M > CAP) M = CAP;

    for (int j = tid; j < 128; j += 512) cnt2[j] = 0;
    for (int i = tid; i < 128 * RSTRIDE; i += 512) stag2[i] = (unsigned short)NN;
    __syncthreads();

    if (tid < nd) stag2[tid * RSTRIDE] = (unsigned short)(d0 + tid);  // self: i=0 -> (g=0,s=0)

    for (int i = tid; i < M; i += 512) {
        unsigned int v = temp[base + i];
        int row = (v >> 16) & 127;
        int r = atomicAdd(&cnt2[row], 1);
        int idx = 1 + r;
        if (idx < RSTRIDE) stag2[row * RSTRIDE + (idx & 15) * 8 + (idx >> 4)] = (unsigned short)(v & 0xFFFFu);
    }
    __syncthreads();

    if (tid < nd) dinv[d0 + tid] = rsqrtf((float)(cnt2[tid] + 1));  // +1 self-loop

    const int tot = nd * RSTRIDE;
    for (int i = tid; i < tot; i += 512) col16[(size_t)d0 * RSTRIDE + i] = stag2[i];
}

// ---------------- GEMM layer 0 (epilogue writes split y halves) ----------------
__global__ __launch_bounds__(256) void gemm0_mfma(const float* __restrict__ x, const unsigned short* __restrict__ WT,
                                                  const float* __restrict__ dinv,
                                                  unsigned short* __restrict__ ylo, unsigned short* __restrict__ yhi) {
    __shared__ unsigned short As[2][64 * 72];
    const int tid = threadIdx.x;
    const int wv = tid >> 6, lane = tid & 63;
    const int mn = lane & 15, quad = lane >> 4;
    const int row0 = blockIdx.x * 64;

    f32x4 acc[4];
#pragma unroll
    for (int t = 0; t < 4; ++t) acc[t] = (f32x4){0.f, 0.f, 0.f, 0.f};

    float4 ld[4];
#pragma unroll
    for (int it = 0; it < 4; ++it) {
        int i = tid + 256 * it;
        int row = i >> 4, c4 = (i & 15) << 2;
        int gr = row0 + row;
        ld[it] = (gr < NN) ? *(const float4*)(x + (size_t)gr * 256 + c4) : make_float4(0.f, 0.f, 0.f, 0.f);
    }
#pragma unroll
    for (int it = 0; it < 4; ++it) {
        int i = tid + 256 * it;
        int row = i >> 4, c4 = (i & 15) << 2;
        ushort4 o;
        o.x = f2bf(ld[it].x); o.y = f2bf(ld[it].y); o.z = f2bf(ld[it].z); o.w = f2bf(ld[it].w);
        *(ushort4*)&As[0][row * 72 + c4] = o;
    }
    __syncthreads();

    int cur = 0;
    for (int k0 = 0; k0 < 256; k0 += 64) {
        if (k0 < 192) {
#pragma unroll
            for (int it = 0; it < 4; ++it) {
                int i = tid + 256 * it;
                int row = i >> 4, c4 = (i & 15) << 2;
                int gr = row0 + row;
                ld[it] = (gr < NN) ? *(const float4*)(x + (size_t)gr * 256 + (k0 + 64) + c4)
                                   : make_float4(0.f, 0.f, 0.f, 0.f);
            }
        }
#pragma unroll
        for (int kk = 0; kk < 2; ++kk) {
            bf16x8 a = *(const bf16x8*)&As[cur][(wv * 16 + mn) * 72 + kk * 32 + quad * 8];
#pragma unroll
            for (int t = 0; t < 4; ++t) {
                bf16x8 bfr = *(const bf16x8*)(WT + (t * 16 + mn) * 256 + k0 + kk * 32 + quad * 8);
                acc[t] = __builtin_amdgcn_mfma_f32_16x16x32_bf16(a, bfr, acc[t], 0, 0, 0);
            }
        }
        if (k0 < 192) {
#pragma unroll
            for (int it = 0; it < 4; ++it) {
                int i = tid + 256 * it;
                int row = i >> 4, c4 = (i & 15) << 2;
                ushort4 o;
                o.x = f2bf(ld[it].x); o.y = f2bf(ld[it].y); o.z = f2bf(ld[it].z); o.w = f2bf(ld[it].w);
                *(ushort4*)&As[cur ^ 1][row * 72 + c4] = o;
            }
            __syncthreads();
            cur ^= 1;
        }
    }
    __syncthreads();
    float dv[4];
#pragma unroll
    for (int r = 0; r < 4; ++r) {
        int gr = row0 + wv * 16 + quad * 4 + r;
        dv[r] = (gr < NN) ? dinv[gr] : 0.f;
    }
#pragma unroll
    for (int t = 0; t < 4; ++t)
#pragma unroll
        for (int r = 0; r < 4; ++r)
            As[0][(wv * 16 + quad * 4 + r) * 72 + t * 16 + mn] = f2bf(acc[t][r] * dv[r]);
    __syncthreads();
#pragma unroll
    for (int it = 0; it < 2; ++it) {
        int i = tid + 256 * it;
        int row = i >> 3, c8 = (i & 7) << 3;
        int gr = row0 + row;
        if (gr < NN) {
            uint4 v = *(uint4*)&As[0][row * 72 + c8];
            if (c8 < 32) *(uint4*)(ylo + (size_t)gr * 32 + c8) = v;
            else *(uint4*)(yhi + (size_t)gr * 32 + (c8 - 32)) = v;
        }
    }
    if (blockIdx.x == 0 && tid < 4) {
        uint4 z = {0u, 0u, 0u, 0u};
        *(uint4*)(ylo + (size_t)NN * 32 + tid * 8) = z;
        *(uint4*)(yhi + (size_t)NN * 32 + tid * 8) = z;
    }
}

// ---------------- gather one half-row set: 16 groups x 4 lanes, L2-resident half-matrix ----------------
// q[s] = neighbor id for slot s (i = s*16+g); pads = NN (zero row). r[8] = half-row elems l*8..l*8+7.
__device__ __forceinline__ void agg_half(const unsigned short* __restrict__ yh, us8 q,
                                         int b16, float dvw, const float* __restrict__ bb,
                                         float* __restrict__ r) {
    const unsigned short PADV = (unsigned short)NN;
    int skipA = __all((q[2] == PADV) && (q[3] == PADV));
    int skipB = __all((q[4] == PADV) && (q[5] == PADV) && (q[6] == PADV) && (q[7] == PADV));

    float2 acc[4] = {{0.f, 0.f}, {0.f, 0.f}, {0.f, 0.f}, {0.f, 0.f}};
    {
        uint4 v0 = *(const uint4*)(yh + ((unsigned)q[0]) * 32 + b16);
        uint4 v1 = *(const uint4*)(yh + ((unsigned)q[1]) * 32 + b16);
        acc_u4(acc, v0); acc_u4(acc, v1);
    }
    if (!skipA) {
        uint4 v2 = *(const uint4*)(yh + ((unsigned)q[2]) * 32 + b16);
        uint4 v3 = *(const uint4*)(yh + ((unsigned)q[3]) * 32 + b16);
        acc_u4(acc, v2); acc_u4(acc, v3);
    }
    if (!skipB) {
        uint4 v4 = *(const uint4*)(yh + ((unsigned)q[4]) * 32 + b16);
        uint4 v5 = *(const uint4*)(yh + ((unsigned)q[5]) * 32 + b16);
        uint4 v6 = *(const uint4*)(yh + ((unsigned)q[6]) * 32 + b16);
        uint4 v7 = *(const uint4*)(yh + ((unsigned)q[7]) * 32 + b16);
        acc_u4(acc, v4); acc_u4(acc, v5); acc_u4(acc, v6); acc_u4(acc, v7);
    }
#pragma unroll
    for (int j = 0; j < 4; ++j) {
        float sx = acc[j].x;
        float sy = acc[j].y;
        sx += __shfl_xor(sx, 4); sx += __shfl_xor(sx, 8); sx += __shfl_xor(sx, 16); sx += __shfl_xor(sx, 32);
        sy += __shfl_xor(sy, 4); sy += __shfl_xor(sy, 8); sy += __shfl_xor(sy, 16); sy += __shfl_xor(sy, 32);
        r[2 * j] = dvw * sx + bb[2 * j];
        r[2 * j + 1] = dvw * sy + bb[2 * j + 1];
    }
}

// ---------------- Fused aggregate(8 dsts/wave, lo-pass then hi-pass) + GEMM 64x64, 512 threads ----------------
template <int RELU>
__global__ __launch_bounds__(512) void aggH_gemm(const unsigned short* __restrict__ ylo,
                                                 const unsigned short* __restrict__ yhi,
                                                 const unsigned short* __restrict__ col16,
                                                 const float* __restrict__ dinv,
                                                 const float* __restrict__ bias,
                                                 const unsigned short* __restrict__ WT,
                                                 unsigned short* __restrict__ yolo,
                                                 unsigned short* __restrict__ yohi) {
    __shared__ unsigned short As[64 * 72];
    const int tid = threadIdx.x;
    const int wv = tid >> 6, lane = tid & 63;
    const int g = lane >> 2, l = lane & 3;
    const int b16 = l << 3;  // shorts offset within 32-short half row
    const int row0 = blockIdx.x * 64;
    const int d0 = row0 + wv * 8;

    // prefetch all 8 dsts' col slots + dinv
    us8 q0, q1, q2, q3, q4, q5, q6, q7;
    float dvs[8];
    {
        int dc;
#define LDQ(T, QV)                                                              \
        dc = (d0 + T < NN) ? (d0 + T) : (NN - 1);                               \
        QV = *(const us8*)(col16 + (size_t)dc * RSTRIDE + g * 8);               \
        dvs[T] = dinv[dc];
        LDQ(0, q0) LDQ(1, q1) LDQ(2, q2) LDQ(3, q3)
        LDQ(4, q4) LDQ(5, q5) LDQ(6, q6) LDQ(7, q7)
#undef LDQ
    }
    float bbl[8], bbh[8];
    *(float4*)&bbl[0] = *(const float4*)(bias + b16);
    *(float4*)&bbl[4] = *(const float4*)(bias + b16 + 4);
    *(float4*)&bbh[0] = *(const float4*)(bias + 32 + b16);
    *(float4*)&bbh[4] = *(const float4*)(bias + 32 + b16 + 4);

    // ---- pass over halves: h=0 uses ylo (3.2MB, L2-resident), h=1 uses yhi ----
#define DO_DST(T, QV, HALF, YH, BB)                                             \
    {                                                                           \
        const int d = d0 + T;                                                   \
        float r[8];                                                             \
        if (d < NN) {                                                           \
            agg_half(YH, QV, b16, dvs[T], BB, r);                               \
            if (RELU) {                                                         \
                for (int j = 0; j < 8; ++j) r[j] = fmaxf(r[j], 0.f);            \
            }                                                                   \
        } else {                                                                \
            for (int j = 0; j < 8; ++j) r[j] = 0.f;                            \
        }                                                                       \
        if (g == 0) {                                                           \
            uint4 o;                                                            \
            o.x = (unsigned)f2bf(r[0]) | ((unsigned)f2bf(r[1]) << 16);          \
            o.y = (unsigned)f2bf(r[2]) | ((unsigned)f2bf(r[3]) << 16);          \
            o.z = (unsigned)f2bf(r[4]) | ((unsigned)f2bf(r[5]) << 16);          \
            o.w = (unsigned)f2bf(r[6]) | ((unsigned)f2bf(r[7]) << 16);          \
            *(uint4*)&As[(wv * 8 + T) * 72 + HALF * 32 + b16] = o;              \
        }                                                                       \
    }
    DO_DST(0, q0, 0, ylo, bbl) DO_DST(1, q1, 0, ylo, bbl) DO_DST(2, q2, 0, ylo, bbl) DO_DST(3, q3, 0, ylo, bbl)
    DO_DST(4, q4, 0, ylo, bbl) DO_DST(5, q5, 0, ylo, bbl) DO_DST(6, q6, 0, ylo, bbl) DO_DST(7, q7, 0, ylo, bbl)
    DO_DST(0, q0, 1, yhi, bbh) DO_DST(1, q1, 1, yhi, bbh) DO_DST(2, q2, 1, yhi, bbh) DO_DST(3, q3, 1, yhi, bbh)
    DO_DST(4, q4, 1, yhi, bbh) DO_DST(5, q5, 1, yhi, bbh) DO_DST(6, q6, 1, yhi, bbh) DO_DST(7, q7, 1, yhi, bbh)
#undef DO_DST
    __syncthreads();

    // ---- GEMM 64x64 from LDS A; wave (wr,wc): rows wr*16..+15 x cols wc*32..+31 ----
    const int mn = lane & 15, quad = lane >> 4;
    const int wr = wv & 3, wc = wv >> 2;
    f32x4 acc[2];
#pragma unroll
    for (int t = 0; t < 2; ++t) acc[t] = (f32x4){0.f, 0.f, 0.f, 0.f};
#pragma unroll
    for (int kk = 0; kk < 2; ++kk) {
        bf16x8 a = *(const bf16x8*)&As[(wr * 16 + mn) * 72 + kk * 32 + quad * 8];
#pragma unroll
        for (int t = 0; t < 2; ++t) {
            bf16x8 bfr = *(const bf16x8*)(WT + ((wc * 32 + t * 16 + mn) << 6) + kk * 32 + quad * 8);
            acc[t] = __builtin_amdgcn_mfma_f32_16x16x32_bf16(a, bfr, acc[t], 0, 0, 0);
        }
    }
    __syncthreads();
    float dv[4];
#pragma unroll
    for (int r = 0; r < 4; ++r) {
        int gr = row0 + wr * 16 + quad * 4 + r;
        dv[r] = (gr < NN) ? dinv[gr] : 0.f;
    }
#pragma unroll
    for (int t = 0; t < 2; ++t)
#pragma unroll
        for (int r = 0; r < 4; ++r)
            As[(wr * 16 + quad * 4 + r) * 72 + wc * 32 + t * 16 + mn] = f2bf(acc[t][r] * dv[r]);
    __syncthreads();
    {
        int row = tid >> 3, c8 = (tid & 7) << 3;
        int gr = row0 + row;
        if (gr < NN) {
            uint4 v = *(uint4*)&As[row * 72 + c8];
            if (c8 < 32) *(uint4*)(yolo + (size_t)gr * 32 + c8) = v;
            else *(uint4*)(yohi + (size_t)gr * 32 + (c8 - 32)) = v;
        }
    }
    if (blockIdx.x == 0 && tid < 4) {
        uint4 z = {0u, 0u, 0u, 0u};
        *(uint4*)(yolo + (size_t)NN * 32 + tid * 8) = z;
        *(uint4*)(yohi + (size_t)NN * 32 + tid * 8) = z;
    }
}

// ---------------- Layer-2 aggregate + head + fused loss ----------------
__global__ __launch_bounds__(256) void aggregate_final_kernel(const unsigned short* __restrict__ ylo,
                                                              const unsigned short* __restrict__ yhi,
                                                              const unsigned short* __restrict__ col16,
                                                              const float* __restrict__ dinv,
                                                              const float* __restrict__ b,
                                                              const float* __restrict__ W3, const float* __restrict__ b3,
                                                              const int* __restrict__ labels,
                                                              const int* __restrict__ train_cnt,
                                                              float* __restrict__ loss_ws, int* __restrict__ done_ct,
                                                              float* __restrict__ out) {
    const int tid = threadIdx.x;
    const int wv = tid >> 6, lane = tid & 63;
    const int g = lane >> 2, l = lane & 3;
    const int b16 = l << 3;
    const int d = blockIdx.x * 4 + wv;

    float bbl[8], bbh[8];
    *(float4*)&bbl[0] = *(const float4*)(b + b16);
    *(float4*)&bbl[4] = *(const float4*)(b + b16 + 4);
    *(float4*)&bbh[0] = *(const float4*)(b + 32 + b16);
    *(float4*)&bbh[4] = *(const float4*)(b + 32 + b16 + 4);

    us8 q = *(const us8*)(col16 + (size_t)d * RSTRIDE + g * 8);
    const float dvw = dinv[d];
    float rlo[8], rhi[8];
    agg_half(ylo, q, b16, dvw, bbl, rlo);
    agg_half(yhi, q, b16, dvw, bbh, rhi);
#pragma unroll
    for (int j = 0; j < 8; ++j) {
        rlo[j] = fmaxf(rlo[j], 0.f);
        rhi[j] = fmaxf(rhi[j], 0.f);
    }

    float sq = 0.f;
#pragma unroll
    for (int j = 0; j < 8; ++j) sq += rlo[j] * rlo[j] + rhi[j] * rhi[j];
    sq += __shfl_xor(sq, 1);
    sq += __shfl_xor(sq, 2);
    float inv = 1.0f / fmaxf(sqrtf(sq), 1e-12f);

    __shared__ float hl[4][68];
    if (g == 0) {
        float4 a0 = make_float4(rlo[0] * inv, rlo[1] * inv, rlo[2] * inv, rlo[3] * inv);
        float4 a1 = make_float4(rlo[4] * inv, rlo[5] * inv, rlo[6] * inv, rlo[7] * inv);
        float4 a2 = make_float4(rhi[0] * inv, rhi[1] * inv, rhi[2] * inv, rhi[3] * inv);
        float4 a3 = make_float4(rhi[4] * inv, rhi[5] * inv, rhi[6] * inv, rhi[7] * inv);
        float* op = out + 1 + (size_t)NN * C_DIM + (size_t)d * 64;
        *(float4*)(op + b16) = a0;
        *(float4*)(op + b16 + 4) = a1;
        *(float4*)(op + 32 + b16) = a2;
        *(float4*)(op + 32 + b16 + 4) = a3;
        *(float4*)&hl[wv][b16] = a0;
        *(float4*)&hl[wv][b16 + 4] = a1;
        *(float4*)&hl[wv][32 + b16] = a2;
        *(float4*)&hl[wv][32 + b16 + 4] = a3;
    }
    __syncthreads();

    int c = lane & 15, chunk = lane >> 4;
    float part = 0.f;
#pragma unroll
    for (int qq = 0; qq < 16; ++qq) {
        int hh = chunk * 16 + qq;
        part += hl[wv][hh] * W3[hh * 16 + c];
    }
    part += __shfl_xor(part, 16);
    part += __shfl_xor(part, 32);
    float logit = part + b3[c];

    float m = logit;
#pragma unroll
    for (int off = 8; off > 0; off >>= 1) m = fmaxf(m, __shfl_xor(m, off));
    float ex = __expf(logit - m);
    float se = ex;
#pragma unroll
    for (int off = 8; off > 0; off >>= 1) se += __shfl_xor(se, off);
    float pred = logit - m - __logf(se);
    if (lane < 16) out[1 + (size_t)d * 16 + lane] = pred;

    // fused loss: this dst contributes train_cnt[d] * (-pred[labels[d]])
    int tc = train_cnt[d];
    if (tc > 0) {
        int lab = labels[d];
        if (lane == lab) atomicAdd(loss_ws, -pred * (float)tc);
    }
    __syncthreads();
    if (tid == 0) {
        __threadfence();
        int prev = atomicAdd(done_ct, 1);
        if (prev == (int)gridDim.x - 1) {
            float total = atomicAdd(loss_ws, 0.0f);
            out[0] = total * (1.0f / NT);
        }
    }
}

// ---------------- launch ----------------

extern "C" void kernel_launch(void* const* d_in, const int* in_sizes, int n_in,
                              void* d_out, int out_size, void* d_ws, size_t ws_size,
                              hipStream_t stream) {
    const float* feats = (const float*)d_in[0];
    const float* W1 = (const float*)d_in[1];
    const float* b1 = (const float*)d_in[2];
    const float* W2 = (const float*)d_in[3];
    const float* b2 = (const float*)d_in[4];
    const float* W3 = (const float*)d_in[5];
    const float* b3 = (const float*)d_in[6];
    const int* edge_list = (const int*)d_in[7];
    const int* labels = (const int*)d_in[8];
    const int* train_idx = (const int*)d_in[9];
    float* out = (float*)d_out;

    char* w = (char*)d_ws;
    auto alloc = [&](size_t bytes) {
        char* p = w;
        w += (bytes + 255) & ~(size_t)255;
        return p;
    };
    unsigned short* col16 = (unsigned short*)alloc((size_t)NN * RSTRIDE * 2);
    unsigned int* temp = (unsigned int*)alloc((size_t)NBUK * PAD * 4);
    float* dinv = (float*)alloc((size_t)NN * 4);
    unsigned short* ylo = (unsigned short*)alloc((size_t)(NN + 8) * 32 * 2);
    unsigned short* yhi = (unsigned short*)alloc((size_t)(NN + 8) * 32 * 2);
    unsigned short* zlo = (unsigned short*)alloc((size_t)(NN + 8) * 32 * 2);
    unsigned short* zhi = (unsigned short*)alloc((size_t)(NN + 8) * 32 * 2);
    unsigned short* WT1 = (unsigned short*)alloc((size_t)64 * 256 * 2);
    unsigned short* WT2 = (unsigned short*)alloc((size_t)2 * 64 * 64 * 2);
    float* loss_ws = (float*)alloc(4);
    int* cursor = (int*)alloc((size_t)NBUK * 4);
    int* done_ct = (int*)alloc(4);
    int* train_cnt = (int*)alloc((size_t)NN * 4);

    const int* srcp = edge_list;
    const int* dstp = edge_list + EE;

    init_kernel<<<196, 256, 0, stream>>>(W1, W2, WT1, WT2, cursor, loss_ws, done_ct, train_cnt);
    multisplit_kernel<<<NCHUNK, 512, 0, stream>>>(srcp, dstp, cursor, temp);
    bucket_finalize_kernel<<<NBUK, 512, 0, stream>>>(temp, cursor, dinv, col16, train_idx, train_cnt);

    const int GB = (NN + 63) / 64;  // 782
    // layer 0 GEMM
    gemm0_mfma<<<GB, 256, 0, stream>>>(feats, WT1, dinv, ylo, yhi);
    // layer 0 aggregate (b1, no relu) fused with layer-1 GEMM (W2[0])
    aggH_gemm<0><<<GB, 512, 0, stream>>>(ylo, yhi, col16, dinv, b1, WT2, zlo, zhi);
    // layer 1 aggregate (b2[0], relu) fused with layer-2 GEMM (W2[1])
    aggH_gemm<1><<<GB, 512, 0, stream>>>(zlo, zhi, col16, dinv, b2, WT2 + 4096, ylo, yhi);
    // layer 2 aggregate + head + loss
    aggregate_final_kernel<<<NN / 4, 256, 0, stream>>>(ylo, yhi, col16, dinv, b2 + H_DIM, W3, b3,
                                                       labels, train_cnt, loss_ws, done_ct, out);
}

// Round 12
// 247.981 us; speedup vs baseline: 2.8885x; 2.8885x over previous
//
#include <hip/hip_runtime.h>
#include <math.h>

#define NN 50000
#define EE 1600000
#define IN_DIM 256
#define H_DIM 64
#define C_DIM 16
#define NT 5000
#define NBUK 391  // ceil(NN/128)
#define CHUNK 4096
#define NCHUNK 391  // ceil(EE/CHUNK)
#define PAD 6144   // per-bucket temp capacity (expected load ~4092+slack)
#define CAP 6144
#define RSTRIDE 96  // 8 groups x 12 slots, group-major; neighbor idx i -> (i&7)*12 + (i>>3)

typedef short bf16x8 __attribute__((ext_vector_type(8)));
typedef float f32x4 __attribute__((ext_vector_type(4)));

__device__ __forceinline__ unsigned short f2bf(float f) {
    unsigned int u = __float_as_uint(f);
    u = (u + 0x7FFFu + ((u >> 16) & 1u)) >> 16;  // RNE
    return (unsigned short)u;
}
// bf16x2 dword accumulate via v_dot2_f32_bf16 (bit-identical to extract+add).
__device__ __forceinline__ void acc_dw(float2& a, unsigned u) {
    asm("v_dot2_f32_bf16 %0, %1, %2, %0" : "+v"(a.x) : "v"(u), "v"(0x00003F80u));
    asm("v_dot2_f32_bf16 %0, %1, %2, %0" : "+v"(a.y) : "v"(u), "v"(0x3F800000u));
}
__device__ __forceinline__ void acc_u4(float2* acc, uint4 v) {
    acc_dw(acc[0], v.x); acc_dw(acc[1], v.y); acc_dw(acc[2], v.z); acc_dw(acc[3], v.w);
}

// ---------------- init: cursors, loss, done flag, bf16-transposed weights ----------------
__global__ __launch_bounds__(256) void init_kernel(const float* __restrict__ W1, const float* __restrict__ W2,
                                                   unsigned short* __restrict__ WT1, unsigned short* __restrict__ WT2,
                                                   int* __restrict__ cursor, float* __restrict__ loss_ws,
                                                   int* __restrict__ done_ct) {
    int i = blockIdx.x * 256 + threadIdx.x;
    if (i < NBUK) cursor[i] = i * PAD;
    if (i == 0) { loss_ws[0] = 0.f; done_ct[0] = 0; }
    if (i < 64 * 256) {
        int n = i >> 8, k = i & 255;
        WT1[i] = f2bf(W1[k * 64 + n]);
    }
    int j = i - 64 * 256;
    if (j >= 0 && j < 2 * 64 * 64) {
        int l = j >> 12, r = j & 4095;
        int n = r >> 6, k = r & 63;
        WT2[j] = f2bf(W2[l * 4096 + k * 64 + n]);
    }
}

// ---------------- multisplit (verified) ----------------
__global__ __launch_bounds__(512) void multisplit_kernel(const int* __restrict__ src, const int* __restrict__ dst,
                                                         int* __restrict__ cursor, unsigned int* __restrict__ temp) {
    __shared__ int hist[NBUK];
    __shared__ int excl[NBUK + 1];
    __shared__ int offs[NBUK];
    __shared__ int delta[NBUK];
    __shared__ unsigned int stag[CHUNK];
    __shared__ unsigned short sdl[CHUNK];

    const int tid = threadIdx.x;
    const int base_e = blockIdx.x * CHUNK;

    for (int i = tid; i < NBUK; i += 512) hist[i] = 0;
    __syncthreads();

    for (int i = tid; i < CHUNK; i += 512) {
        int e = base_e + i;
        if (e < EE) {
            int d = dst[e];
            atomicAdd(&hist[d >> 7], 1);
            sdl[i] = (unsigned short)d;
        }
    }
    __syncthreads();

    if (tid < 64) {
        int lane = tid;
        int lc[7];
        int s = 0;
#pragma unroll
        for (int k = 0; k < 7; ++k) {
            int idx = lane * 7 + k;
            int c = (idx < NBUK) ? hist[idx] : 0;
            lc[k] = c;
            s += c;
        }
        int v = s;
#pragma unroll
        for (int off = 1; off < 64; off <<= 1) {
            int u = __shfl_up(v, off);
            if (lane >= off) v += u;
        }
        int ex = v - s;
#pragma unroll
        for (int k = 0; k < 7; ++k) {
            int idx = lane * 7 + k;
            if (idx < NBUK) excl[idx] = ex;
            ex += lc[k];
        }
        if (lane == 63) excl[NBUK] = v;
    }
    __syncthreads();

    for (int b = tid; b < NBUK; b += 512) {
        int count = excl[b + 1] - excl[b];
        int gbase = atomicAdd(&cursor[b], count);
        delta[b] = gbase - excl[b];
        offs[b] = excl[b];
    }
    __syncthreads();

    for (int i = tid; i < CHUNK; i += 512) {
        int e = base_e + i;
        if (e < EE) {
            unsigned int dv = sdl[i];
            int b = (int)(dv >> 7);
            int rank = atomicAdd(&offs[b], 1);
            stag[rank] = ((unsigned)b << 23) | ((dv & 127u) << 16) | (unsigned)src[e];
        }
    }
    __syncthreads();

    int nval = excl[NBUK];
    for (int i = tid; i < nval; i += 512) {
        unsigned int v = stag[i];
        temp[delta[v >> 23] + i] = v & 0x7FFFFFu;
    }
}

// ---------------- per-bucket finalize: fixed-stride group-major rows (verified) ----------------
__global__ __launch_bounds__(512) void bucket_finalize_kernel(const unsigned int* __restrict__ temp,
                                                              const int* __restrict__ cursor,
                                                              float* __restrict__ dinv,
                                                              unsigned short* __restrict__ col16) {
    __shared__ int cnt2[128];
    __shared__ unsigned short stag2[128 * RSTRIDE];  // 24 KB
    const int b = blockIdx.x;
    const int tid = threadIdx.x;
    const int d0 = b << 7;
    const int nd = (d0 + 128 < NN) ? 128 : (NN - d0);
    const int base = b * PAD;
    int M = cursor[b] - base;
    if (M > CAP) M = CAP;

    for (int j = tid; j < 128; j += 512) cnt2[j] = 0;
    for (int i = tid; i < 128 * RSTRIDE; i += 512) stag2[i] = (unsigned short)NN;
    __syncthreads();

    if (tid < nd) stag2[tid * RSTRIDE] = (unsigned short)(d0 + tid);  // self: i=0 -> (g=0,s=0)

    for (int i = tid; i < M; i += 512) {
        unsigned int v = temp[base + i];
        int row = (v >> 16) & 127;
        int r = atomicAdd(&cnt2[row], 1);
        int idx = 1 + r;
        if (idx < RSTRIDE) stag2[row * RSTRIDE + (idx & 7) * 12 + (idx >> 3)] = (unsigned short)(v & 0xFFFFu);
    }
    __syncthreads();

    if (tid < nd) dinv[d0 + tid] = rsqrtf((float)(cnt2[tid] + 1));  // +1 self-loop

    const int tot = nd * RSTRIDE;
    for (int i = tid; i < tot; i += 512) col16[(size_t)d0 * RSTRIDE + i] = stag2[i];
}

// ---------------- GEMM layer 0: fp32 feats, double-buffered LDS staging x WT1 ----------------
__global__ __launch_bounds__(256) void gemm0_mfma(const float* __restrict__ x, const unsigned short* __restrict__ WT,
                                                  const float* __restrict__ dinv, unsigned short* __restrict__ y) {
    __shared__ unsigned short As[2][64 * 72];
    const int tid = threadIdx.x;
    const int wv = tid >> 6, lane = tid & 63;
    const int mn = lane & 15, quad = lane >> 4;
    const int row0 = blockIdx.x * 64;

    f32x4 acc[4];
#pragma unroll
    for (int t = 0; t < 4; ++t) acc[t] = (f32x4){0.f, 0.f, 0.f, 0.f};

    float4 ld[4];
#pragma unroll
    for (int it = 0; it < 4; ++it) {
        int i = tid + 256 * it;
        int row = i >> 4, c4 = (i & 15) << 2;
        int gr = row0 + row;
        ld[it] = (gr < NN) ? *(const float4*)(x + (size_t)gr * 256 + c4) : make_float4(0.f, 0.f, 0.f, 0.f);
    }
#pragma unroll
    for (int it = 0; it < 4; ++it) {
        int i = tid + 256 * it;
        int row = i >> 4, c4 = (i & 15) << 2;
        ushort4 o;
        o.x = f2bf(ld[it].x); o.y = f2bf(ld[it].y); o.z = f2bf(ld[it].z); o.w = f2bf(ld[it].w);
        *(ushort4*)&As[0][row * 72 + c4] = o;
    }
    __syncthreads();

    int cur = 0;
    for (int k0 = 0; k0 < 256; k0 += 64) {
        if (k0 < 192) {
#pragma unroll
            for (int it = 0; it < 4; ++it) {
                int i = tid + 256 * it;
                int row = i >> 4, c4 = (i & 15) << 2;
                int gr = row0 + row;
                ld[it] = (gr < NN) ? *(const float4*)(x + (size_t)gr * 256 + (k0 + 64) + c4)
                                   : make_float4(0.f, 0.f, 0.f, 0.f);
            }
        }
#pragma unroll
        for (int kk = 0; kk < 2; ++kk) {
            bf16x8 a = *(const bf16x8*)&As[cur][(wv * 16 + mn) * 72 + kk * 32 + quad * 8];
#pragma unroll
            for (int t = 0; t < 4; ++t) {
                bf16x8 bfr = *(const bf16x8*)(WT + (t * 16 + mn) * 256 + k0 + kk * 32 + quad * 8);
                acc[t] = __builtin_amdgcn_mfma_f32_16x16x32_bf16(a, bfr, acc[t], 0, 0, 0);
            }
        }
        if (k0 < 192) {
#pragma unroll
            for (int it = 0; it < 4; ++it) {
                int i = tid + 256 * it;
                int row = i >> 4, c4 = (i & 15) << 2;
                ushort4 o;
                o.x = f2bf(ld[it].x); o.y = f2bf(ld[it].y); o.z = f2bf(ld[it].z); o.w = f2bf(ld[it].w);
                *(ushort4*)&As[cur ^ 1][row * 72 + c4] = o;
            }
            __syncthreads();
            cur ^= 1;
        }
    }
    __syncthreads();
    float dv[4];
#pragma unroll
    for (int r = 0; r < 4; ++r) {
        int gr = row0 + wv * 16 + quad * 4 + r;
        dv[r] = (gr < NN) ? dinv[gr] : 0.f;
    }
#pragma unroll
    for (int t = 0; t < 4; ++t)
#pragma unroll
        for (int r = 0; r < 4; ++r)
            As[0][(wv * 16 + quad * 4 + r) * 72 + t * 16 + mn] = f2bf(acc[t][r] * dv[r]);
    __syncthreads();
#pragma unroll
    for (int it = 0; it < 2; ++it) {
        int i = tid + 256 * it;
        int row = i >> 3, c8 = (i & 7) << 3;
        int gr = row0 + row;
        if (gr < NN) *(uint4*)(y + (size_t)gr * 64 + c8) = *(uint4*)&As[0][row * 72 + c8];
    }
    if (blockIdx.x == 0 && tid < 8) {
        uint4 z = {0u, 0u, 0u, 0u};
        *(uint4*)(y + (size_t)NN * 64 + tid * 8) = z;
    }
}

// ---------------- Aggregate core (q's preloaded; dot2 accumulate) ----------------
__device__ __forceinline__ void agg_core(const unsigned short* __restrict__ y,
                                         ushort4 q0, ushort4 q1, ushort4 q2,
                                         int g, int h0, float dvw,
                                         const float* __restrict__ bb, float* __restrict__ r) {
    const unsigned short PADV = (unsigned short)NN;
    int skipA = __all((q1.y == PADV) && (q1.z == PADV) && (q1.w == PADV));
    int skipB = __all((q2.x == PADV) && (q2.y == PADV) && (q2.z == PADV) && (q2.w == PADV));

    float2 acc[4] = {{0.f, 0.f}, {0.f, 0.f}, {0.f, 0.f}, {0.f, 0.f}};
    {
        uint4 v0 = *(const uint4*)(y + (((unsigned)q0.x) << 6) + h0);
        uint4 v1 = *(const uint4*)(y + (((unsigned)q0.y) << 6) + h0);
        uint4 v2 = *(const uint4*)(y + (((unsigned)q0.z) << 6) + h0);
        uint4 v3 = *(const uint4*)(y + (((unsigned)q0.w) << 6) + h0);
        uint4 v4 = *(const uint4*)(y + (((unsigned)q1.x) << 6) + h0);
        acc_u4(acc, v0); acc_u4(acc, v1); acc_u4(acc, v2); acc_u4(acc, v3); acc_u4(acc, v4);
    }
    if (!skipA) {
        uint4 v5 = *(const uint4*)(y + (((unsigned)q1.y) << 6) + h0);
        uint4 v6 = *(const uint4*)(y + (((unsigned)q1.z) << 6) + h0);
        uint4 v7 = *(const uint4*)(y + (((unsigned)q1.w) << 6) + h0);
        acc_u4(acc, v5); acc_u4(acc, v6); acc_u4(acc, v7);
    }
    if (!skipB) {
        uint4 v8 = *(const uint4*)(y + (((unsigned)q2.x) << 6) + h0);
        uint4 v9 = *(const uint4*)(y + (((unsigned)q2.y) << 6) + h0);
        uint4 va = *(const uint4*)(y + (((unsigned)q2.z) << 6) + h0);
        uint4 vb = *(const uint4*)(y + (((unsigned)q2.w) << 6) + h0);
        acc_u4(acc, v8); acc_u4(acc, v9); acc_u4(acc, va); acc_u4(acc, vb);
    }
#pragma unroll
    for (int j = 0; j < 4; ++j) {
        float sx = acc[j].x;
        float sy = acc[j].y;
        sx += __shfl_xor(sx, 8); sx += __shfl_xor(sx, 16); sx += __shfl_xor(sx, 32);
        sy += __shfl_xor(sy, 8); sy += __shfl_xor(sy, 16); sy += __shfl_xor(sy, 32);
        r[2 * j] = dvw * sx + bb[2 * j];
        r[2 * j + 1] = dvw * sy + bb[2 * j + 1];
    }
}

// ---------------- Fused aggregate(8 dsts/wave -> LDS) + GEMM 64x64, 512 threads ----------------
// 8 waves: gather phase has 2x the TLP of the 256-thread version. GEMM splits 8 ways
// (wave (wr,wc): rows wr*16..+15, cols wc*32..+31). Barriers around cross-wave LDS reuse.
template <int RELU>
__global__ __launch_bounds__(512) void aggH_gemm(const unsigned short* __restrict__ y,
                                                 const unsigned short* __restrict__ col16,
                                                 const float* __restrict__ dinv,
                                                 const float* __restrict__ bias,
                                                 const unsigned short* __restrict__ WT,
                                                 unsigned short* __restrict__ yout) {
    __shared__ unsigned short As[64 * 72];
    const int tid = threadIdx.x;
    const int wv = tid >> 6, lane = tid & 63;
    const int g = lane >> 3, l = lane & 7;
    const int h0 = l << 3;
    const int row0 = blockIdx.x * 64;
    const int d0 = row0 + wv * 8;

    float bb[8];
    *(float4*)&bb[0] = *(const float4*)(bias + h0);
    *(float4*)&bb[4] = *(const float4*)(bias + h0 + 4);

    // ---- phase 1: aggregate 8 dsts (col16 prefetched one dst ahead) ----
    int dcl = (d0 < NN) ? d0 : (NN - 1);
    const unsigned short* cp = col16 + (size_t)dcl * RSTRIDE + g * 12;
    ushort4 nq0 = *(const ushort4*)(cp);
    ushort4 nq1 = *(const ushort4*)(cp + 4);
    ushort4 nq2 = *(const ushort4*)(cp + 8);
    for (int t = 0; t < 8; ++t) {
        ushort4 q0 = nq0, q1 = nq1, q2 = nq2;
        if (t < 7) {
            int dn = d0 + t + 1;
            dcl = (dn < NN) ? dn : (NN - 1);
            const unsigned short* cp2 = col16 + (size_t)dcl * RSTRIDE + g * 12;
            nq0 = *(const ushort4*)(cp2);
            nq1 = *(const ushort4*)(cp2 + 4);
            nq2 = *(const ushort4*)(cp2 + 8);
        }
        const int d = d0 + t;
        float r[8];
        if (d < NN) {
            agg_core(y, q0, q1, q2, g, h0, dinv[d], bb, r);
            if (RELU) {
#pragma unroll
                for (int j = 0; j < 8; ++j) r[j] = fmaxf(r[j], 0.f);
            }
        } else {
#pragma unroll
            for (int j = 0; j < 8; ++j) r[j] = 0.f;
        }
        if (g == 0) {
            uint4 o;
            o.x = (unsigned)f2bf(r[0]) | ((unsigned)f2bf(r[1]) << 16);
            o.y = (unsigned)f2bf(r[2]) | ((unsigned)f2bf(r[3]) << 16);
            o.z = (unsigned)f2bf(r[4]) | ((unsigned)f2bf(r[5]) << 16);
            o.w = (unsigned)f2bf(r[6]) | ((unsigned)f2bf(r[7]) << 16);
            *(uint4*)&As[(wv * 8 + t) * 72 + h0] = o;
        }
    }
    __syncthreads();

    // ---- phase 2: GEMM 64x64 from LDS A; wave (wr,wc) does rows wr*16..+15 x cols wc*32..+31 ----
    const int mn = lane & 15, quad = lane >> 4;
    const int wr = wv & 3, wc = wv >> 2;
    f32x4 acc[2];
#pragma unroll
    for (int t = 0; t < 2; ++t) acc[t] = (f32x4){0.f, 0.f, 0.f, 0.f};
#pragma unroll
    for (int kk = 0; kk < 2; ++kk) {
        bf16x8 a = *(const bf16x8*)&As[(wr * 16 + mn) * 72 + kk * 32 + quad * 8];
#pragma unroll
        for (int t = 0; t < 2; ++t) {
            bf16x8 bfr = *(const bf16x8*)(WT + ((wc * 32 + t * 16 + mn) << 6) + kk * 32 + quad * 8);
            acc[t] = __builtin_amdgcn_mfma_f32_16x16x32_bf16(a, bfr, acc[t], 0, 0, 0);
        }
    }
    __syncthreads();  // all A-fragment reads complete before epilogue overwrites As
    float dv[4];
#pragma unroll
    for (int r = 0; r < 4; ++r) {
        int gr = row0 + wr * 16 + quad * 4 + r;
        dv[r] = (gr < NN) ? dinv[gr] : 0.f;
    }
#pragma unroll
    for (int t = 0; t < 2; ++t)
#pragma unroll
        for (int r = 0; r < 4; ++r)
            As[(wr * 16 + quad * 4 + r) * 72 + wc * 32 + t * 16 + mn] = f2bf(acc[t][r] * dv[r]);
    __syncthreads();
    {
        int row = tid >> 3, c8 = (tid & 7) << 3;
        int gr = row0 + row;
        if (gr < NN) *(uint4*)(yout + (size_t)gr * 64 + c8) = *(uint4*)&As[row * 72 + c8];
    }
    if (blockIdx.x == 0 && tid < 8) {
        uint4 z = {0u, 0u, 0u, 0u};
        *(uint4*)(yout + (size_t)NN * 64 + tid * 8) = z;
    }
}

// ---------------- Layer-2 aggregate fused head ----------------
__global__ __launch_bounds__(256) void aggregate_final_kernel(const unsigned short* __restrict__ y,
                                                              const unsigned short* __restrict__ col16,
                                                              const float* __restrict__ dinv,
                                                              const float* __restrict__ b,
                                                              const float* __restrict__ W3, const float* __restrict__ b3,
                                                              float* __restrict__ out) {
    const int tid = threadIdx.x;
    const int wv = tid >> 6, lane = tid & 63;
    const int g = lane >> 3, l = lane & 7;
    const int h0 = l << 3;
    const int d = blockIdx.x * 4 + wv;

    float bb[8];
    *(float4*)&bb[0] = *(const float4*)(b + h0);
    *(float4*)&bb[4] = *(const float4*)(b + h0 + 4);

    const unsigned short* cp = col16 + (size_t)d * RSTRIDE + g * 12;
    ushort4 q0 = *(const ushort4*)(cp);
    ushort4 q1 = *(const ushort4*)(cp + 4);
    ushort4 q2 = *(const ushort4*)(cp + 8);
    float r[8];
    agg_core(y, q0, q1, q2, g, h0, dinv[d], bb, r);
#pragma unroll
    for (int j = 0; j < 8; ++j) r[j] = fmaxf(r[j], 0.f);

    float sq = 0.f;
#pragma unroll
    for (int j = 0; j < 8; ++j) sq += r[j] * r[j];
    sq += __shfl_xor(sq, 1);
    sq += __shfl_xor(sq, 2);
    sq += __shfl_xor(sq, 4);
    float inv = 1.0f / fmaxf(sqrtf(sq), 1e-12f);

    __shared__ float hl[4][68];
    if (g == 0) {
        float4 hA = make_float4(r[0] * inv, r[1] * inv, r[2] * inv, r[3] * inv);
        float4 hB = make_float4(r[4] * inv, r[5] * inv, r[6] * inv, r[7] * inv);
        float* op = out + 1 + (size_t)NN * C_DIM + (size_t)d * 64 + h0;
        *(float4*)op = hA;
        *(float4*)(op + 4) = hB;
        *(float4*)&hl[wv][h0] = hA;
        *(float4*)&hl[wv][h0 + 4] = hB;
    }
    __syncthreads();

    int c = lane & 15, chunk = lane >> 4;
    float part = 0.f;
#pragma unroll
    for (int q = 0; q < 16; ++q) {
        int hh = chunk * 16 + q;
        part += hl[wv][hh] * W3[hh * 16 + c];
    }
    part += __shfl_xor(part, 16);
    part += __shfl_xor(part, 32);
    float logit = part + b3[c];

    float m = logit;
#pragma unroll
    for (int off = 8; off > 0; off >>= 1) m = fmaxf(m, __shfl_xor(m, off));
    float ex = __expf(logit - m);
    float se = ex;
#pragma unroll
    for (int off = 8; off > 0; off >>= 1) se += __shfl_xor(se, off);
    float pred = logit - m - __logf(se);
    if (lane < 16) out[1 + (size_t)d * 16 + lane] = pred;
}

// loss + fused finalize (last block writes out[0])
__global__ __launch_bounds__(256) void loss_kernel(const float* __restrict__ outr, const int* __restrict__ labels,
                                                   const int* __restrict__ train_idx, float* __restrict__ loss_ws,
                                                   int* __restrict__ done_ct, float* __restrict__ out) {
    int i = blockIdx.x * 256 + threadIdx.x;
    float v = 0.f;
    if (i < NT) {
        int idx = train_idx[i];
        int lab = labels[idx];
        v = -outr[1 + (size_t)idx * 16 + lab];
    }
#pragma unroll
    for (int off = 32; off > 0; off >>= 1) v += __shfl_xor(v, off);
    __shared__ float ws4[4];
    int wv = threadIdx.x >> 6, lane = threadIdx.x & 63;
    if (lane == 0) ws4[wv] = v;
    __syncthreads();
    if (threadIdx.x == 0) {
        atomicAdd(loss_ws, ws4[0] + ws4[1] + ws4[2] + ws4[3]);
        __threadfence();
        int prev = atomicAdd(done_ct, 1);
        if (prev == (int)gridDim.x - 1) {
            float total = atomicAdd(loss_ws, 0.0f);  // coherent read of final sum
            out[0] = total * (1.0f / NT);
        }
    }
}

// ---------------- launch ----------------

extern "C" void kernel_launch(void* const* d_in, const int* in_sizes, int n_in,
                              void* d_out, int out_size, void* d_ws, size_t ws_size,
                              hipStream_t stream) {
    const float* feats = (const float*)d_in[0];
    const float* W1 = (const float*)d_in[1];
    const float* b1 = (const float*)d_in[2];
    const float* W2 = (const float*)d_in[3];
    const float* b2 = (const float*)d_in[4];
    const float* W3 = (const float*)d_in[5];
    const float* b3 = (const float*)d_in[6];
    const int* edge_list = (const int*)d_in[7];
    const int* labels = (const int*)d_in[8];
    const int* train_idx = (const int*)d_in[9];
    float* out = (float*)d_out;

    char* w = (char*)d_ws;
    auto alloc = [&](size_t bytes) {
        char* p = w;
        w += (bytes + 255) & ~(size_t)255;
        return p;
    };
    unsigned short* col16 = (unsigned short*)alloc((size_t)NN * RSTRIDE * 2);
    unsigned int* temp = (unsigned int*)alloc((size_t)NBUK * PAD * 4);
    float* dinv = (float*)alloc((size_t)NN * 4);
    unsigned short* yb = (unsigned short*)alloc((size_t)(NN + 64) * 64 * 2);
    unsigned short* yc = (unsigned short*)alloc((size_t)(NN + 64) * 64 * 2);
    unsigned short* WT1 = (unsigned short*)alloc((size_t)64 * 256 * 2);
    unsigned short* WT2 = (unsigned short*)alloc((size_t)2 * 64 * 64 * 2);
    float* loss_ws = (float*)alloc(4);
    int* cursor = (int*)alloc((size_t)NBUK * 4);
    int* done_ct = (int*)alloc(4);

    const int* srcp = edge_list;
    const int* dstp = edge_list + EE;

    init_kernel<<<96, 256, 0, stream>>>(W1, W2, WT1, WT2, cursor, loss_ws, done_ct);
    multisplit_kernel<<<NCHUNK, 512, 0, stream>>>(srcp, dstp, cursor, temp);
    bucket_finalize_kernel<<<NBUK, 512, 0, stream>>>(temp, cursor, dinv, col16);

    const int GB = (NN + 63) / 64;  // 782
    // layer 0 GEMM
    gemm0_mfma<<<GB, 256, 0, stream>>>(feats, WT1, dinv, yb);
    // layer 0 aggregate (b1, no relu) fused with layer-1 GEMM (W2[0])
    aggH_gemm<0><<<GB, 512, 0, stream>>>(yb, col16, dinv, b1, WT2, yc);
    // layer 1 aggregate (b2[0], relu) fused with layer-2 GEMM (W2[1])
    aggH_gemm<1><<<GB, 512, 0, stream>>>(yc, col16, dinv, b2, WT2 + 4096, yb);
    // layer 2 aggregate + head
    aggregate_final_kernel<<<NN / 4, 256, 0, stream>>>(yb, col16, dinv, b2 + H_DIM, W3, b3, out);

    loss_kernel<<<(NT + 255) / 256, 256, 0, stream>>>(out, labels, train_idx, loss_ws, done_ct, out);
}